// Round 5
// baseline (93.707 us; speedup 1.0000x reference)
//
#include <hip/hip_runtime.h>

#define BB 4
#define NN 2048
#define DD 256
#define GCX 40                    // 640/16 cells in x
#define GCY 30                    // 480/16 cells in y
#define NCELL (GCX * GCY)         // 1200
#define CSTRIDE 1216              // starts row stride (ints), 1201 used
#define OCTW 5                    // cell columns per octant (8 octants x 5 = 40)
#define STILE 256                 // src points per match block (1 per thread)
#define NTIL (NN / STILE)         // 8
#define MBLK (BB * BB * NTIL * 8) // 1024 match blocks = 4/CU
#define WQ_CAP 160                // per-wave hit queue

// ws layout (bytes) — total ~532 KB of the 256 MiB workspace
#define OFF_BX    131072                       // float2[16][2048] = 262144
#define OFF_BM    (131072 + 262144)            // int[16][2048]    = 131072
#define OFF_PSUM  (131072 + 262144 + 131072)   // float[1024]
#define OFF_PCNT  (OFF_PSUM + 4096)            // uint[1024]

__device__ __forceinline__ int cell_clamp(int v, int hi) {
    return v < 0 ? 0 : (v > hi ? hi : v);
}

// Kernel 1: per-pair counting sort of dst points into 16px cells.
// Stores DENORMED coords (same fmaf(r,s,s) as ever) so the match kernel's
// d2 test consumes bit-identical values to the verified brute-force path.
// Cell indices are clamped defensively (removes the only theoretically
// unbounded LDS index in the pipeline; no effect for in-range inputs).
__global__ __launch_bounds__(256) void build_kernel(const float* __restrict__ pts_dst,
                                                    const int* __restrict__ hptr,
                                                    const int* __restrict__ wptr,
                                                    int* __restrict__ starts,
                                                    float2* __restrict__ bx,
                                                    int* __restrict__ bm) {
    __shared__ int cnt[NCELL];                           // counts -> scatter cursors
    __shared__ int tsum[256];
    const int pair = blockIdx.x;
    const float sx = ((float)(*wptr) - 1.0f) * 0.5f;
    const float sy = ((float)(*hptr) - 1.0f) * 0.5f;

    for (int t = threadIdx.x; t < NCELL; t += 256) cnt[t] = 0;
    __syncthreads();

    // pass 1: denorm + count (8 points/thread, coalesced)
    const float2* pd = (const float2*)(pts_dst + (size_t)pair * NN * 2);
    float qx[8], qy[8]; int qc[8];
#pragma unroll
    for (int k = 0; k < 8; ++k) {
        const float2 r = pd[threadIdx.x + k * 256];
        qx[k] = fmaf(r.x, sx, sx);                       // exact same denorm form
        qy[k] = fmaf(r.y, sy, sy);
        const int cx = cell_clamp((int)(qx[k] * 0.0625f), GCX - 1);
        const int cy = cell_clamp((int)(qy[k] * 0.0625f), GCY - 1);
        qc[k] = cx + GCX * cy;
        atomicAdd(&cnt[qc[k]], 1);
    }
    __syncthreads();

    // exclusive prefix over 1200 cells: 5 cells/thread + Hillis-Steele over 256
    const int base = threadIdx.x * 5;
    int loc[5]; int s = 0;
#pragma unroll
    for (int k = 0; k < 5; ++k) {
        const int c = base + k;
        const int v = (c < NCELL) ? cnt[c] : 0;
        loc[k] = s; s += v;
    }
    tsum[threadIdx.x] = s;
    __syncthreads();
    for (int off = 1; off < 256; off <<= 1) {
        const int v = (threadIdx.x >= off) ? tsum[threadIdx.x - off] : 0;
        __syncthreads();
        tsum[threadIdx.x] += v;
        __syncthreads();
    }
    const int tbase = tsum[threadIdx.x] - s;             // exclusive thread base
    int* gst = starts + pair * CSTRIDE;
#pragma unroll
    for (int k = 0; k < 5; ++k) {
        const int c = base + k;
        if (c < NCELL) {
            const int st = tbase + loc[k];
            gst[c] = st;                                 // global cell starts
            cnt[c] = st;                                 // LDS scatter cursor
        }
    }
    if (threadIdx.x == 0) gst[NCELL] = NN;               // sentinel end
    __syncthreads();

    // pass 2: scatter denormed points + original m index
    float2* gbx = bx + (size_t)pair * NN;
    int*    gbm = bm + (size_t)pair * NN;
#pragma unroll
    for (int k = 0; k < 8; ++k) {
        const int pos = atomicAdd(&cnt[qc[k]], 1);       // pos < NN by construction
        gbx[pos] = make_float2(qx[k], qy[k]);
        gbm[pos] = threadIdx.x + k * 256;
    }
}

// Kernel 2: block = (pair, src-tile of 256, cell-column octant). One thread
// per src point walks its 3x3 cell neighborhood (intersected with the
// octant's 5 columns -> each candidate tested exactly once grid-wide).
// Cells >= 2 apart are > 8px away (exact on the denormed floats), so the
// 3x3 neighborhood is a candidate superset; the d2 test is bit-identical
// to the verified brute force => identical hit set.
__global__ __launch_bounds__(256, 4) void match_kernel(const float* __restrict__ feat,
                                                       const float* __restrict__ pts_src,
                                                       const int* __restrict__ hptr,
                                                       const int* __restrict__ wptr,
                                                       const int* __restrict__ starts,
                                                       const float2* __restrict__ bx,
                                                       const int* __restrict__ bm,
                                                       float* __restrict__ psum,
                                                       unsigned int* __restrict__ pcnt) {
    __shared__ unsigned int wq[4][WQ_CAP];               // per-wave hit queues
    __shared__ unsigned int wqc[4];
    __shared__ float bsum[4];
    __shared__ unsigned int bcnt[4];

    const int xcd  = blockIdx.x & 7;                     // round-robin -> XCD
    const int slot = blockIdx.x >> 3;                    // 0..127
    const int pair = (xcd << 1) | (slot >> 6);           // 2 pairs/XCD (L2 reuse)
    const int rest = slot & 63;
    const int tile = rest >> 3;                          // 0..7
    const int oct  = rest & 7;                           // 0..7
    const int i = pair >> 2;
    const int j = pair & 3;
    const float sx = ((float)(*wptr) - 1.0f) * 0.5f;
    const float sy = ((float)(*hptr) - 1.0f) * 0.5f;

    const int wave = threadIdx.x >> 6;
    const int lane = threadIdx.x & 63;
    if (lane == 0) wqc[wave] = 0u;                       // same-wave order: no barrier

    const int nloc = threadIdx.x;                        // src point of this thread
    const float2 r = ((const float2*)pts_src)[(size_t)i * NN + tile * STILE + nloc];
    const float px = fmaf(r.x, sx, sx);
    const float py = fmaf(r.y, sy, sy);
    const int cxs = cell_clamp((int)(px * 0.0625f), GCX - 1);
    const int cys = cell_clamp((int)(py * 0.0625f), GCY - 1);

    const int*    gst = starts + pair * CSTRIDE;
    const float2* gbx = bx + (size_t)pair * NN;
    const int*    gbm = bm + (size_t)pair * NN;

#pragma unroll
    for (int dy = -1; dy <= 1; ++dy) {
        const int cy2 = cys + dy;
        if ((unsigned)cy2 >= (unsigned)GCY) continue;
#pragma unroll
        for (int dx = -1; dx <= 1; ++dx) {
            const int cx2 = cxs + dx;
            if ((unsigned)(cx2 - oct * OCTW) >= (unsigned)OCTW) continue; // octant + bounds
            const int c = cx2 + GCX * cy2;
            const int e = gst[c + 1];
            for (int idx = gst[c]; idx < e; ++idx) {
                const float2 q = gbx[idx];
                const float ax = px - q.x, ay = py - q.y;
                if (fmaf(ax, ax, ay * ay) <= 64.0f) {    // identical d2 test
                    const unsigned int s2 = atomicAdd(&wqc[wave], 1u);
                    if (s2 < WQ_CAP) wq[wave][s2] = ((unsigned int)nloc << 11) | (unsigned int)idx;
                }
            }
        }
    }

    // ---- tail: 8 hits at a time, 8 lanes/hit; dot + both norms fused ----
    const unsigned int hc = min(wqc[wave], (unsigned int)WQ_CAP);
    const int g = lane >> 3, sub = lane & 7;
    float lsum = 0.0f;
    for (unsigned int h0 = 0; h0 < hc; h0 += 8) {
        const unsigned int hid = h0 + (unsigned int)g;
        const bool valid = hid < hc;
        float dd = 0.0f, aa = 0.0f, bb = 0.0f;
        if (valid) {
            const unsigned int rec = wq[wave][hid];
            const int m = gbm[rec & 2047u];
            const int n = tile * STILE + (int)(rec >> 11);
            const float4* pa = (const float4*)(feat + (size_t)(j * NN + n) * DD);
            const float4* pb = (const float4*)(feat + (size_t)(i * NN + m) * DD);
#pragma unroll
            for (int t = 0; t < 8; ++t) {
                const float4 a = pa[t * 8 + sub];
                const float4 b = pb[t * 8 + sub];
                dd = fmaf(a.x, b.x, fmaf(a.y, b.y, fmaf(a.z, b.z, fmaf(a.w, b.w, dd))));
                aa = fmaf(a.x, a.x, fmaf(a.y, a.y, fmaf(a.z, a.z, fmaf(a.w, a.w, aa))));
                bb = fmaf(b.x, b.x, fmaf(b.y, b.y, fmaf(b.z, b.z, fmaf(b.w, b.w, bb))));
            }
        }
        dd += __shfl_xor(dd, 1, 64);  aa += __shfl_xor(aa, 1, 64);  bb += __shfl_xor(bb, 1, 64);
        dd += __shfl_xor(dd, 2, 64);  aa += __shfl_xor(aa, 2, 64);  bb += __shfl_xor(bb, 2, 64);
        dd += __shfl_xor(dd, 4, 64);  aa += __shfl_xor(aa, 4, 64);  bb += __shfl_xor(bb, 4, 64);
        if (valid && sub == 0) {
            const float p = aa * bb;                     // (|fa|*|fb|)^2 >> eps^2
            float rr = rsqrtf(p);
            rr = rr * (1.5f - 0.5f * p * rr * rr);       // one Newton step
            lsum += 1.0f - dd * rr;
        }
    }
#pragma unroll
    for (int off = 32; off >= 1; off >>= 1) lsum += __shfl_xor(lsum, off, 64);

    // ---- block reduction -> private slot (plain stores, no atomics) ----
    if (lane == 0) { bsum[wave] = lsum; bcnt[wave] = hc; }
    __syncthreads();
    if (threadIdx.x == 0) {
        psum[blockIdx.x] = bsum[0] + bsum[1] + bsum[2] + bsum[3];
        pcnt[blockIdx.x] = bcnt[0] + bcnt[1] + bcnt[2] + bcnt[3];
    }
}

// Kernel 3: reduce the 1024 block partials. One block.
__global__ __launch_bounds__(256) void finalize_kernel(const float* __restrict__ psum,
                                                       const unsigned int* __restrict__ pcnt,
                                                       float* __restrict__ out) {
    float s = 0.0f;
    float c = 0.0f;                                      // hits < 2^24, exact in f32
    for (int t = threadIdx.x; t < MBLK; t += 256) {
        s += psum[t];
        c += (float)pcnt[t];
    }
#pragma unroll
    for (int off = 32; off >= 1; off >>= 1) {
        s += __shfl_xor(s, off, 64);
        c += __shfl_xor(c, off, 64);
    }
    __shared__ float ss[4], cc[4];
    const int wave = threadIdx.x >> 6;
    const int lane = threadIdx.x & 63;
    if (lane == 0) { ss[wave] = s; cc[wave] = c; }
    __syncthreads();
    if (threadIdx.x == 0) {
        const float S = ss[0] + ss[1] + ss[2] + ss[3];
        const float C = cc[0] + cc[1] + cc[2] + cc[3];
        out[0] = S / fmaxf(C, 1.0f);                     // max(cnt, 1)
    }
}

extern "C" void kernel_launch(void* const* d_in, const int* in_sizes, int n_in,
                              void* d_out, int out_size, void* d_ws, size_t ws_size,
                              hipStream_t stream) {
    const float* feat    = (const float*)d_in[0];   // [B,N,D] f32
    const float* pts_src = (const float*)d_in[1];   // [B,N,2] f32
    const float* pts_dst = (const float*)d_in[2];   // [B,B,N,2] f32
    // d_in[3] = invis_idx — unused by the reference
    const int* hptr = (const int*)d_in[4];          // height (scalar)
    const int* wptr = (const int*)d_in[5];          // width  (scalar)
    float* out = (float*)d_out;

    int*          starts = (int*)d_ws;                               // 16 x 1216 ints
    float2*       bx     = (float2*)((char*)d_ws + OFF_BX);          // 16 x 2048 float2
    int*          bm     = (int*)((char*)d_ws + OFF_BM);             // 16 x 2048 int
    float*        psum   = (float*)((char*)d_ws + OFF_PSUM);         // 1024 floats
    unsigned int* pcnt   = (unsigned int*)((char*)d_ws + OFF_PCNT);  // 1024 uints

    build_kernel<<<BB * BB, 256, 0, stream>>>(pts_dst, hptr, wptr, starts, bx, bm);
    match_kernel<<<MBLK, 256, 0, stream>>>(feat, pts_src, hptr, wptr,
                                           starts, bx, bm, psum, pcnt);
    finalize_kernel<<<1, 256, 0, stream>>>(psum, pcnt, out);
}

// Round 6
// 92.758 us; speedup vs baseline: 1.0102x; 1.0102x over previous
//
#include <hip/hip_runtime.h>

#define BB 4
#define NN 2048
#define DD 256
#define GCX 40                    // 640/16 cells in x
#define GCY 30                    // 480/16 cells in y
#define NCELL (GCX * GCY)         // 1200
#define STILE 128                 // src points per block
#define NTIL (NN / STILE)         // 16
#define NBLK (BB * BB * NTIL)     // 256 blocks = 1/CU
#define WQ_CAP 256                // per-wave hit queue (lambda ~43, 6x mean)

// Poison-proof record tags (protocol HW-proven in round 2, absmax 0.0):
// constant fill P can't satisfy P==KEY1^bid AND P==KEY2^bid (KEY1!=KEY2).
#define KEY1 0xA5C3E7D1u
#define KEY2 0x3B9ACA07u

__device__ __forceinline__ int cell_clamp(int v, int hi) {
    return v < 0 ? 0 : (v > hi ? hi : v);
}

// ONE dispatch. Block = (pair, src-tile of 128).
//  * Redundant per-block counting sort of the pair's 2048 dst points into
//    LDS (math verbatim from the absmax-0.0 round-5 build kernel).
//  * Walk: per src point, 3 contiguous cell-ranges (one per row of the 3x3
//    neighborhood) read from LDS. 2 lanes/src split rows. Cells >=2 apart
//    are >8px away (exact on denormed floats) => candidate superset; the
//    d2 test is bit-identical to the verified brute force => same hit set.
//  * Last-arriver finalize: tagged 16B record per block, one non-spinning
//    read pass over all 256 tags; all-valid => compute fixed-order
//    reduction, write out. No wait loops => no deadlock possible.
__global__ __launch_bounds__(256) void fused_kernel(const float* __restrict__ feat,
                                                    const float* __restrict__ pts_src,
                                                    const float* __restrict__ pts_dst,
                                                    const int* __restrict__ hptr,
                                                    const int* __restrict__ wptr,
                                                    unsigned int* __restrict__ recs,
                                                    float* __restrict__ out) {
    __shared__ float2 bpts[NN];                          // 16 KB denormed dst pts
    __shared__ unsigned short bmid[NN];                  // 4 KB original m index
    __shared__ int st[NCELL + 1];                        // cell starts + sentinel
    __shared__ int cur[NCELL];                           // counts -> cursors
    __shared__ int tsum[256];                            // prefix scratch
    __shared__ unsigned int wq[4][WQ_CAP];               // per-wave hit queues
    __shared__ unsigned int wqc[4];
    __shared__ float bsum[4];
    __shared__ unsigned int bcnt[4];
    __shared__ float rs[4], rc[4];                       // reducer cross-wave

    const int xcd  = blockIdx.x & 7;                     // round-robin -> XCD
    const int rest = blockIdx.x >> 3;                    // 0..31
    const int pair = (xcd << 1) | (rest >> 4);           // 2 pairs/XCD (share dst batch i)
    const int tile = rest & 15;
    const int i = pair >> 2;
    const int j = pair & 3;
    const float sx = ((float)(*wptr) - 1.0f) * 0.5f;
    const float sy = ((float)(*hptr) - 1.0f) * 0.5f;

    const int wave = threadIdx.x >> 6;
    const int lane = threadIdx.x & 63;
    if (lane == 0) wqc[wave] = 0u;                       // reset before the bin barrier

    // ---- per-block LDS counting sort of this pair's 2048 dst points ----
    for (int t = threadIdx.x; t < NCELL; t += 256) cur[t] = 0;
    __syncthreads();

    const float2* pd = (const float2*)(pts_dst + (size_t)pair * NN * 2);
    float qx[8], qy[8]; int qc[8];
#pragma unroll
    for (int k = 0; k < 8; ++k) {
        const float2 r = pd[threadIdx.x + k * 256];
        qx[k] = fmaf(r.x, sx, sx);                       // exact same denorm form
        qy[k] = fmaf(r.y, sy, sy);
        const int cx = cell_clamp((int)(qx[k] * 0.0625f), GCX - 1);
        const int cy = cell_clamp((int)(qy[k] * 0.0625f), GCY - 1);
        qc[k] = cx + GCX * cy;
        atomicAdd(&cur[qc[k]], 1);
    }
    __syncthreads();

    // exclusive prefix over 1200 cells: 5/thread + Hillis-Steele over 256
    const int base = threadIdx.x * 5;
    int loc[5]; int s = 0;
#pragma unroll
    for (int k = 0; k < 5; ++k) {
        const int c = base + k;
        const int v = (c < NCELL) ? cur[c] : 0;
        loc[k] = s; s += v;
    }
    tsum[threadIdx.x] = s;
    __syncthreads();
    for (int off = 1; off < 256; off <<= 1) {
        const int v = (threadIdx.x >= off) ? tsum[threadIdx.x - off] : 0;
        __syncthreads();
        tsum[threadIdx.x] += v;
        __syncthreads();
    }
    const int tbase = tsum[threadIdx.x] - s;             // exclusive thread base
#pragma unroll
    for (int k = 0; k < 5; ++k) {
        const int c = base + k;
        if (c < NCELL) st[c] = tbase + loc[k];
    }
    if (threadIdx.x == 0) st[NCELL] = NN;                // sentinel end
    __syncthreads();
    for (int t = threadIdx.x; t < NCELL; t += 256) cur[t] = st[t];
    __syncthreads();
#pragma unroll
    for (int k = 0; k < 8; ++k) {
        const int pos = atomicAdd(&cur[qc[k]], 1);       // pos < NN by construction
        bpts[pos] = make_float2(qx[k], qy[k]);
        bmid[pos] = (unsigned short)(threadIdx.x + k * 256);
    }

    // ---- src point for this thread (2 lanes per src, rows split) ----
    const int sub = threadIdx.x & 1;                     // 0: rows -1,+1   1: row 0
    const int sl  = threadIdx.x >> 1;                    // 0..127 local src id
    const int n   = tile * STILE + sl;
    const float2 r = ((const float2*)pts_src)[(size_t)i * NN + n];
    const float px = fmaf(r.x, sx, sx);
    const float py = fmaf(r.y, sy, sy);
    const int cxs = cell_clamp((int)(px * 0.0625f), GCX - 1);
    const int cys = cell_clamp((int)(py * 0.0625f), GCY - 1);
    const int cxlo = cxs > 0 ? cxs - 1 : 0;
    const int cxhi = cxs < GCX - 1 ? cxs + 1 : GCX - 1;
    __syncthreads();                                     // bins ready

    // ---- walk: contiguous LDS range per row of the 3x3 neighborhood ----
#pragma unroll
    for (int rsel = 0; rsel < 2; ++rsel) {
        if (sub == 1 && rsel == 1) continue;
        const int dy = (sub == 1) ? 0 : (rsel == 0 ? -1 : 1);
        const int cy2 = cys + dy;
        if ((unsigned)cy2 >= (unsigned)GCY) continue;
        const int b0 = st[cy2 * GCX + cxlo];
        const int e0 = st[cy2 * GCX + cxhi + 1];
        for (int idx = b0; idx < e0; ++idx) {
            const float2 q = bpts[idx];
            const float ax = px - q.x, ay = py - q.y;
            if (fmaf(ax, ax, ay * ay) <= 64.0f) {        // identical d2 test
                const unsigned int s2 = atomicAdd(&wqc[wave], 1u);
                if (s2 < WQ_CAP) wq[wave][s2] = ((unsigned int)sl << 11) | (unsigned int)idx;
            }
        }
    }

    // ---- tail: 8 hits at a time, 8 lanes/hit; dot + both norms fused ----
    const unsigned int hc = min(wqc[wave], (unsigned int)WQ_CAP);
    const int g = lane >> 3, sb = lane & 7;
    float lsum = 0.0f;
    for (unsigned int h0 = 0; h0 < hc; h0 += 8) {
        const unsigned int hid = h0 + (unsigned int)g;
        const bool valid = hid < hc;
        float dd = 0.0f, aa = 0.0f, bb = 0.0f;
        if (valid) {
            const unsigned int rec = wq[wave][hid];
            const int m = (int)bmid[rec & 2047u];
            const int nn2 = tile * STILE + (int)(rec >> 11);
            const float4* pa = (const float4*)(feat + (size_t)(j * NN + nn2) * DD);
            const float4* pb = (const float4*)(feat + (size_t)(i * NN + m) * DD);
#pragma unroll
            for (int t = 0; t < 8; ++t) {
                const float4 a = pa[t * 8 + sb];
                const float4 b = pb[t * 8 + sb];
                dd = fmaf(a.x, b.x, fmaf(a.y, b.y, fmaf(a.z, b.z, fmaf(a.w, b.w, dd))));
                aa = fmaf(a.x, a.x, fmaf(a.y, a.y, fmaf(a.z, a.z, fmaf(a.w, a.w, aa))));
                bb = fmaf(b.x, b.x, fmaf(b.y, b.y, fmaf(b.z, b.z, fmaf(b.w, b.w, bb))));
            }
        }
        dd += __shfl_xor(dd, 1, 64);  aa += __shfl_xor(aa, 1, 64);  bb += __shfl_xor(bb, 1, 64);
        dd += __shfl_xor(dd, 2, 64);  aa += __shfl_xor(aa, 2, 64);  bb += __shfl_xor(bb, 2, 64);
        dd += __shfl_xor(dd, 4, 64);  aa += __shfl_xor(aa, 4, 64);  bb += __shfl_xor(bb, 4, 64);
        if (valid && sb == 0) {
            const float p = aa * bb;                     // (|fa|*|fb|)^2 >> eps^2
            float rr = rsqrtf(p);
            rr = rr * (1.5f - 0.5f * p * rr * rr);       // one Newton step
            lsum += 1.0f - dd * rr;
        }
    }
#pragma unroll
    for (int off = 32; off >= 1; off >>= 1) lsum += __shfl_xor(lsum, off, 64);

    // ---- block partial -> tagged record ----
    if (lane == 0) { bsum[wave] = lsum; bcnt[wave] = hc; }
    __syncthreads();
    if (threadIdx.x == 0) {
        const float S = bsum[0] + bsum[1] + bsum[2] + bsum[3];
        const unsigned int C = bcnt[0] + bcnt[1] + bcnt[2] + bcnt[3];
        unsigned int* rec = recs + 4u * blockIdx.x;
        __hip_atomic_store(rec + 0, __float_as_uint(S), __ATOMIC_RELAXED, __HIP_MEMORY_SCOPE_AGENT);
        __hip_atomic_store(rec + 1, C,                  __ATOMIC_RELAXED, __HIP_MEMORY_SCOPE_AGENT);
        __hip_atomic_store(rec + 2, KEY1 ^ (unsigned)blockIdx.x, __ATOMIC_RELEASE, __HIP_MEMORY_SCOPE_AGENT);
        __hip_atomic_store(rec + 3, KEY2 ^ (unsigned)blockIdx.x, __ATOMIC_RELEASE, __HIP_MEMORY_SCOPE_AGENT);
        __threadfence();                                 // own stores visible before read pass
    }
    __syncthreads();

    // ---- last-arriver finalize: ONE read pass, no spin ----
    const int t = threadIdx.x;                           // NBLK == 256 == blockDim
    unsigned int* rrec = recs + 4u * (unsigned int)t;
    const unsigned int w2 = __hip_atomic_load(rrec + 2, __ATOMIC_RELAXED, __HIP_MEMORY_SCOPE_AGENT);
    const unsigned int w3 = __hip_atomic_load(rrec + 3, __ATOMIC_RELAXED, __HIP_MEMORY_SCOPE_AGENT);
    const int tvalid = (w2 == (KEY1 ^ (unsigned)t)) && (w3 == (KEY2 ^ (unsigned)t));
    if (__syncthreads_and(tvalid)) {
        // all 256 records valid: this block is (one of) the last finishers.
        // Fixed-order reduction -> bitwise-identical result whichever block
        // computes it; duplicate out-writes are benign.
        float s = __uint_as_float(__hip_atomic_load(rrec + 0, __ATOMIC_RELAXED, __HIP_MEMORY_SCOPE_AGENT));
        float c = (float)__hip_atomic_load(rrec + 1, __ATOMIC_RELAXED, __HIP_MEMORY_SCOPE_AGENT);
#pragma unroll
        for (int off = 32; off >= 1; off >>= 1) {
            s += __shfl_xor(s, off, 64);
            c += __shfl_xor(c, off, 64);
        }
        if (lane == 0) { rs[wave] = s; rc[wave] = c; }
        __syncthreads();
        if (threadIdx.x == 0) {
            const float S = rs[0] + rs[1] + rs[2] + rs[3];
            const float C = rc[0] + rc[1] + rc[2] + rc[3];
            out[0] = S / fmaxf(C, 1.0f);                 // max(cnt, 1)
        }
    }
}

extern "C" void kernel_launch(void* const* d_in, const int* in_sizes, int n_in,
                              void* d_out, int out_size, void* d_ws, size_t ws_size,
                              hipStream_t stream) {
    const float* feat    = (const float*)d_in[0];   // [B,N,D] f32
    const float* pts_src = (const float*)d_in[1];   // [B,N,2] f32
    const float* pts_dst = (const float*)d_in[2];   // [B,B,N,2] f32
    // d_in[3] = invis_idx — unused by the reference
    const int* hptr = (const int*)d_in[4];          // height (scalar)
    const int* wptr = (const int*)d_in[5];          // width  (scalar)
    float* out = (float*)d_out;

    unsigned int* recs = (unsigned int*)d_ws;       // 256 x 16 B = 4 KB

    fused_kernel<<<NBLK, 256, 0, stream>>>(feat, pts_src, pts_dst,
                                           hptr, wptr, recs, out);
}